// Round 18
// baseline (50.200 us; speedup 1.0000x reference)
//
#include <hip/hip_runtime.h>
#include <math.h>

#define NN   4096
#define NN4  (NN/4)
#define CAP  128      // slots per row; Poisson(64) -> never hit
#define RPB  2        // rows per block
#define D3B  (NN/RPB) // 2048 blocks = 8/CU x 256 CU -> fully resident (LDS ~18KB)
#define NGRP 32       // 32 groups of 64 blocks (barriers + tail)
#define GPAD 32       // ints per counter line (128 B)
#define CPAD 32       // ints per scatter counter line (R14: private line/counter)

// ---- ctr layout (ints from ctr base): two barriers (A,B) + tail cascade ----
#define C_GOA   0                    // 32 go lines, barrier A
#define C_AGRP  (32 * GPAD)          // 32 arrival lines, barrier A
#define C_AGLOB (64 * GPAD)
#define C_GOB   (65 * GPAD)          // 32 go lines, barrier B
#define C_BGRP  (97 * GPAD)          // 32 arrival lines, barrier B
#define C_BGLOB (129 * GPAD)
#define C_TGRP  (130 * GPAD)         // 32 tail lines
#define C_TGLOB (162 * GPAD)
#define CTR_INTS (163 * GPAD)        // 5216 ints ~= 21 KB

// ---- workspace layout (bytes from d_ws) ----
// ctr  @ 0       : 21 KB    barrier/tail counters (zeroed by zerobar node)
// cnt  @ 24576   : 512 KB   NN*CPAD i32, one counter per 128 B line (zeroed in P0)
// entp @ 548864  : 2 MiB    NN*CAP u32 packed col<<8|w (NEVER zeroed: masked reads)
// ND   @ 2646016 : 32 KB    NN u64 packed float2 {N, D3}
// gsum @ 2678784 : 1 KB     NGRP*4 f64
#define OFF_CNT  24576
#define OFF_ENTP 548864
#define OFF_ND   2646016
#define OFF_GSUM 2678784

// ---------------- bootstrap: zero barrier/tail counters only ----------------
// d_ws is poisoned 0xAA once before timing; ctr must start at 0 every call.
__global__ __launch_bounds__(256) void zerobar_kernel(int* __restrict__ ctr) {
    int t = blockIdx.x * 256 + threadIdx.x;
    if (t < CTR_INTS) ctr[t] = 0;
}

// Two-level grid barrier, fully line-spread (R12-proven; R5/R11 lessons):
// arrivals over 32 lines (64 RMWs each, parallel), release over 32 go lines
// (<=64 read-only pollers each). Pre-arrival __syncthreads drains each wave's
// outstanding stores (vmcnt) so all block writes are at the MALL first.
__device__ __forceinline__ void gridbar(int* __restrict__ c, int goOff,
                                        int grpOff, int globOff,
                                        int tid, int bid) {
    __syncthreads();
    if (tid == 0) {
        const int g = bid & 31;
        int v = __hip_atomic_fetch_add(c + grpOff + g * GPAD, 1,
                                       __ATOMIC_RELAXED, __HIP_MEMORY_SCOPE_AGENT);
        if (v == 63) {
            int vg = __hip_atomic_fetch_add(c + globOff, 1,
                                            __ATOMIC_RELAXED, __HIP_MEMORY_SCOPE_AGENT);
            if (vg == NGRP - 1) {
                #pragma unroll
                for (int k = 0; k < NGRP; ++k)
                    __hip_atomic_store(c + goOff + k * GPAD, 1,
                                       __ATOMIC_RELAXED, __HIP_MEMORY_SCOPE_AGENT);
            }
        }
        while (__hip_atomic_load(c + goOff + g * GPAD,
                                 __ATOMIC_RELAXED, __HIP_MEMORY_SCOPE_AGENT) == 0)
            __builtin_amdgcn_s_sleep(8);
    }
    __syncthreads();
}

// ---------------- everything fused: zero cnt -> scatter -> diag3 -> OLS -----
// Coherence (R12-R14 proven): cross-block-visible writes (cnt zeros, entp, ND,
// gsum) are agent-scope write-through (MALL truth; scatter's device RMWs see
// them); bulk entp/cnt reads post-barrier are normal loads (L2 invalidated at
// dispatch start; first touch pulls from MALL). NO threadfence (R4: L2 flush).
// entp is never zeroed: entry reads masked by slot<mi, inner reads masked by
// slot<lmj[item] -- stale/poison slots never consumed.
// All accumulation integer (R17: exact, order-independent -> deterministic;
// native ds_add_u32, no float-CAS storm).
__global__ __launch_bounds__(256, 8) void fused_kernel(
        const int* __restrict__ idx, const float* __restrict__ wgt, int m,
        const int* __restrict__ lst, int nl,
        int* __restrict__ cnt, unsigned* __restrict__ entp,
        unsigned long long* __restrict__ ND, double* __restrict__ gsum,
        int* __restrict__ ctr, float* __restrict__ out) {
    __shared__ int    lrow[NN];      // 16 KB dense int image of current row
    __shared__ int    lcol[CAP];
    __shared__ int    lval[CAP];
    __shared__ int    lmj[CAP];      // per-neighbor entry counts (inner-loop mask)
    __shared__ int    redI[8];
    __shared__ int    flag;
    __shared__ double dsum[4][4];
    __shared__ double wb[2];
    __shared__ double sh[4];

    const int tid  = threadIdx.x;
    const int bid  = blockIdx.x;
    const int gtid = bid * 256 + tid;
    const int warp = tid >> 6, lane = tid & 63;

    // ---- P0: zero the 4096 live cnt words (agent write-through) ----
    if (gtid < NN)
        __hip_atomic_store(cnt + gtid * CPAD, 0, __ATOMIC_RELAXED,
                           __HIP_MEMORY_SCOPE_AGENT);
    gridbar(ctr, C_GOA, C_AGRP, C_AGLOB, tid, bid);

    // ---- P1: scatter edges, symmetrized; agent write-through entries ----
    // A = scatter + A^T - diag(diag): row s gets (d,w), row d gets (s,w) once.
    if (gtid < m) {
        int2 sd = ((const int2*)idx)[gtid];
        int s = sd.x, d = sd.y;
        unsigned ival = (unsigned)(int)wgt[gtid];
        if (ival > 255u) ival = 255u;
        int p = atomicAdd(cnt + s * CPAD, 1);     // device RMW, private line
        if (p < CAP)
            __hip_atomic_store(entp + (size_t)s * CAP + p, ((unsigned)d << 8) | ival,
                               __ATOMIC_RELAXED, __HIP_MEMORY_SCOPE_AGENT);
        if (s != d) {
            int q = atomicAdd(cnt + d * CPAD, 1);
            if (q < CAP)
                __hip_atomic_store(entp + (size_t)d * CAP + q, ((unsigned)s << 8) | ival,
                                   __ATOMIC_RELAXED, __HIP_MEMORY_SCOPE_AGENT);
        }
    }
    gridbar(ctr, C_GOB, C_BGRP, C_BGLOB, tid, bid);

    // ---- P2: diag(A^3)_i + rowsum, 2 rows per block (int, masked) ----
    // diag(A^3)_i = sum_{(j,w) in row i} w * sum_{(k,w') in row j} w' * A_ik.
    {
        const int i0 = bid * RPB;
        int mi_arr[RPB];
        #pragma unroll
        for (int r = 0; r < RPB; ++r) {
            int c = cnt[(i0 + r) * CPAD];
            mi_arr[r] = c > CAP ? CAP : c;
        }
        uint2 q_arr[RPB];
        #pragma unroll
        for (int r = 0; r < RPB; ++r) q_arr[r] = make_uint2(0u, 0u);
        if (tid < 64) {
            #pragma unroll
            for (int r = 0; r < RPB; ++r)
                q_arr[r] = ((const uint2*)(entp + (size_t)(i0 + r) * CAP))[tid];
        }

        int4* l4 = (int4*)lrow;
        for (int rr = 0; rr < RPB; ++rr) {
            const int i = i0 + rr;
            const int mi = mi_arr[rr];
            for (int k = tid; k < NN4; k += 256) l4[k] = make_int4(0, 0, 0, 0);
            __syncthreads();

            int nsum = 0;
            if (tid < 64) {                       // lanes cover slots 2t, 2t+1
                uint2 q = q_arr[rr];
                const bool v0 = (2 * tid)     < mi;
                const bool v1 = (2 * tid + 1) < mi;
                int c0 = v0 ? (int)((q.x >> 8) & 4095u) : 0;
                int c1 = v1 ? (int)((q.y >> 8) & 4095u) : 0;
                int w0 = v0 ? (int)(q.x & 255u) : 0;
                int w1 = v1 ? (int)(q.y & 255u) : 0;
                lcol[2 * tid]     = c0; lval[2 * tid]     = w0;
                lcol[2 * tid + 1] = c1; lval[2 * tid + 1] = w1;
                int m0 = 0, m1 = 0;
                if (v0) { m0 = cnt[c0 * CPAD]; if (m0 > CAP) m0 = CAP; }
                if (v1) { m1 = cnt[c1 * CPAD]; if (m1 > CAP) m1 = CAP; }
                lmj[2 * tid]     = m0;
                lmj[2 * tid + 1] = m1;
                if (w0) atomicAdd(&lrow[c0], w0);   // native ds_add_u32
                if (w1) atomicAdd(&lrow[c1], w1);
                nsum = w0 + w1;
            }
            if (warp == 0) {
                for (int o = 32; o; o >>= 1) nsum += __shfl_down(nsum, o);
                if (lane == 0) redI[0] = nsum;
            }
            __syncthreads();

            // inner: one uint2/lane = whole 128-slot neighbor row; 4 in flight
            int acc = 0;
            const int s0 = 2 * lane, s1 = 2 * lane + 1;
            for (int t = warp; t < mi; t += 16) {
                const int t1 = t + 4, t2 = t + 8, t3 = t + 12;
                const bool b1 = t1 < mi, b2 = t2 < mi, b3 = t3 < mi;
                int c0 = lcol[t];
                int c1 = b1 ? lcol[t1] : 0;
                int c2 = b2 ? lcol[t2] : 0;
                int c3 = b3 ? lcol[t3] : 0;
                int a0 = lval[t];
                int a1 = b1 ? lval[t1] : 0;
                int a2 = b2 ? lval[t2] : 0;
                int a3 = b3 ? lval[t3] : 0;
                int m0 = lmj[t];
                int m1 = b1 ? lmj[t1] : 0;
                int m2 = b2 ? lmj[t2] : 0;
                int m3 = b3 ? lmj[t3] : 0;
                uint2 q0 = ((const uint2*)(entp + (size_t)c0 * CAP))[lane];
                uint2 q1 = ((const uint2*)(entp + (size_t)c1 * CAP))[lane];
                uint2 q2 = ((const uint2*)(entp + (size_t)c2 * CAP))[lane];
                uint2 q3 = ((const uint2*)(entp + (size_t)c3 * CAP))[lane];
                int d0 = (s0 < m0 ? (int)(q0.x & 255u) * lrow[(q0.x >> 8) & 4095u] : 0)
                       + (s1 < m0 ? (int)(q0.y & 255u) * lrow[(q0.y >> 8) & 4095u] : 0);
                int d1 = (s0 < m1 ? (int)(q1.x & 255u) * lrow[(q1.x >> 8) & 4095u] : 0)
                       + (s1 < m1 ? (int)(q1.y & 255u) * lrow[(q1.y >> 8) & 4095u] : 0);
                int d2 = (s0 < m2 ? (int)(q2.x & 255u) * lrow[(q2.x >> 8) & 4095u] : 0)
                       + (s1 < m2 ? (int)(q2.y & 255u) * lrow[(q2.y >> 8) & 4095u] : 0);
                int d3 = (s0 < m3 ? (int)(q3.x & 255u) * lrow[(q3.x >> 8) & 4095u] : 0)
                       + (s1 < m3 ? (int)(q3.y & 255u) * lrow[(q3.y >> 8) & 4095u] : 0);
                acc += a0 * d0 + a1 * d1 + a2 * d2 + a3 * d3;
            }
            for (int o = 32; o; o >>= 1) acc += __shfl_down(acc, o);
            if (lane == 0) redI[4 + warp] = acc;
            __syncthreads();

            if (tid == 0) {
                float2 nd = make_float2((float)redI[0],
                                        (float)(redI[4] + redI[5] + redI[6] + redI[7]));
                unsigned long long bits;
                __builtin_memcpy(&bits, &nd, 8);
                __hip_atomic_store(ND + i, bits, __ATOMIC_RELAXED, __HIP_MEMORY_SCOPE_AGENT);
            }
            __syncthreads();   // lrow/redI reuse across rows
        }
    }

    // ---- cascade tail (non-blocking; only finishers continue) --------------
    if (tid == 0) {
        asm volatile("s_waitcnt vmcnt(0)" ::: "memory");  // drain ND stores
        int v = __hip_atomic_fetch_add(ctr + C_TGRP + (bid >> 6) * GPAD, 1,
                                       __ATOMIC_RELAXED, __HIP_MEMORY_SCOPE_AGENT);
        flag = (v == 63);
    }
    __syncthreads();
    if (!flag) return;

    // group finisher: 64 blocks x 2 rows = 128 rows -> fp64 OLS partials
    const int g = bid >> 6;
    {
        double p1 = 0, p2 = 0, p3 = 0, p4 = 0;
        if (tid < 128) {
            unsigned long long bits = __hip_atomic_load(ND + (g * 128 + tid),
                                                        __ATOMIC_RELAXED, __HIP_MEMORY_SCOPE_AGENT);
            float2 nd; __builtin_memcpy(&nd, &bits, 8);
            double Nd = (double)nd.x;
            double Ed = Nd + 0.5 * (double)nd.y;
            double ln = (double)logf((float)(Nd + 1e-20));
            double le = (double)logf((float)(Ed + 1e-20));
            p1 = ln; p2 = ln * ln; p3 = le; p4 = ln * le;
        }
        for (int o = 32; o; o >>= 1) {
            p1 += __shfl_down(p1, o);
            p2 += __shfl_down(p2, o);
            p3 += __shfl_down(p3, o);
            p4 += __shfl_down(p4, o);
        }
        if (lane == 0) {
            dsum[warp][0] = p1; dsum[warp][1] = p2;
            dsum[warp][2] = p3; dsum[warp][3] = p4;
        }
        __syncthreads();
        if (tid == 0) {
            for (int k = 0; k < 4; ++k) {
                double v = dsum[0][k] + dsum[1][k] + dsum[2][k] + dsum[3][k];
                __hip_atomic_store(gsum + g * 4 + k, v, __ATOMIC_RELAXED,
                                   __HIP_MEMORY_SCOPE_AGENT);
            }
            asm volatile("s_waitcnt vmcnt(0)" ::: "memory");
            int vg = __hip_atomic_fetch_add(ctr + C_TGLOB, 1,
                                            __ATOMIC_RELAXED, __HIP_MEMORY_SCOPE_AGENT);
            flag = (vg == NGRP - 1);
        }
    }
    __syncthreads();
    if (!flag) return;

    // global finisher: sum 32 partials, solve 2x2, residual over targets
    if (warp == 0) {
        double s1 = 0, s2 = 0, t0 = 0, t1 = 0;
        if (lane < NGRP) {
            s1 = __hip_atomic_load(gsum + lane * 4 + 0, __ATOMIC_RELAXED, __HIP_MEMORY_SCOPE_AGENT);
            s2 = __hip_atomic_load(gsum + lane * 4 + 1, __ATOMIC_RELAXED, __HIP_MEMORY_SCOPE_AGENT);
            t0 = __hip_atomic_load(gsum + lane * 4 + 2, __ATOMIC_RELAXED, __HIP_MEMORY_SCOPE_AGENT);
            t1 = __hip_atomic_load(gsum + lane * 4 + 3, __ATOMIC_RELAXED, __HIP_MEMORY_SCOPE_AGENT);
        }
        for (int o = 32; o; o >>= 1) {
            s1 += __shfl_down(s1, o);
            s2 += __shfl_down(s2, o);
            t0 += __shfl_down(t0, o);
            t1 += __shfl_down(t1, o);
        }
        if (lane == 0) {
            double n = (double)NN;
            double det = n * s2 - s1 * s1;
            wb[0] = (n * t1 - s1 * t0) / det;   // w
            wb[1] = (s2 * t0 - s1 * t1) / det;  // b
        }
    }
    __syncthreads();
    const double w = wb[0];
    const double eb = exp(wb[1]);
    const float wf = (float)w;
    double racc = 0;
    for (int p = tid; p < nl; p += 256) {
        int r = lst[p];
        unsigned long long bits = __hip_atomic_load(ND + r, __ATOMIC_RELAXED,
                                                    __HIP_MEMORY_SCOPE_AGENT);
        float2 nd; __builtin_memcpy(&nd, &bits, 8);
        double Nd = (double)nd.x;
        double Ed = Nd + 0.5 * (double)nd.y;
        double pr = (nd.x > 0.f) ? (double)exp2f(wf * log2f(nd.x)) : 0.0;
        double rv = eb * pr - Ed;
        racc += rv * rv;
    }
    for (int o = 32; o; o >>= 1) racc += __shfl_down(racc, o);
    if (lane == 0) sh[warp] = racc;
    __syncthreads();
    if (tid == 0) out[0] = (float)(sh[0] + sh[1] + sh[2] + sh[3]);
}

extern "C" void kernel_launch(void* const* d_in, const int* in_sizes, int n_in,
                              void* d_out, int out_size, void* d_ws, size_t ws_size,
                              hipStream_t stream) {
    const int*   tri_idx = (const int*)d_in[0];
    const float* tri_w   = (const float*)d_in[1];
    const int*   lst     = (const int*)d_in[2];
    const int m  = in_sizes[1];          // number of edges
    const int nl = in_sizes[2];          // number of targets

    char* base = (char*)d_ws;
    int*      ctr  = (int*)base;
    int*      cnt  = (int*)(base + OFF_CNT);
    unsigned* entp = (unsigned*)(base + OFF_ENTP);
    unsigned long long* ND = (unsigned long long*)(base + OFF_ND);
    double*   gsum = (double*)(base + OFF_GSUM);
    float*    out  = (float*)d_out;

    zerobar_kernel<<<(CTR_INTS + 255) / 256, 256, 0, stream>>>(ctr);
    fused_kernel<<<D3B, 256, 0, stream>>>(tri_idx, tri_w, m, lst, nl,
                                          cnt, entp, ND, gsum, ctr, out);
}